// Round 3
// baseline (457.640 us; speedup 1.0000x reference)
//
#include <hip/hip_runtime.h>

#define N_NODES 100000
#define N_EDGES 1600000
#define IN_DIM 128
#define HID 64
#define NB 782               // ceil(100000 / 128) buckets of 128 nodes
#define NBLK_GEMM 782        // ceil(100000 / 128) gemm blocks (128 rows each)
#define NGROUP 25000         // N_NODES / 4 agg groups

typedef __attribute__((ext_vector_type(8))) _Float16 h8v;
typedef __attribute__((ext_vector_type(4))) float f4v;

struct Args {
  const float* x; const int* ei;
  const float* Wp; const float* bp;
  const float* W1; const float* b1;
  const float* W2; const float* b2;
  const float* W3; const float* b3;
  float* out;
  _Float16* bufA16; _Float16* hw16;
  int* pairs; int* csr; int* offs; float* dinv;
  int* bsz; int* bboff; int* bcur;
  int2* meta;
  _Float16* WpH; _Float16* WpL; _Float16* W1H; _Float16* W1L;
  _Float16* W2H; _Float16* W2L; _Float16* W3H; _Float16* W3L;
};

// ---------------- weight prep: split fp32 W[K][64] -> transposed half hi/lo ----
__device__ __forceinline__ void d_split(const float* __restrict__ W,
                                        _Float16* __restrict__ hi,
                                        _Float16* __restrict__ lo, int K, int i) {
  int k = i >> 6, n = i & 63;
  float v = W[i];
  _Float16 h = (_Float16)v;
  float r = v - (float)h;
  hi[n * K + k] = h;
  lo[n * K + k] = (_Float16)r;
}

__global__ __launch_bounds__(256) void f_prep(Args a) {
  int blk = blockIdx.x, t = threadIdx.x;
  if (blk < 32) d_split(a.Wp, a.WpH, a.WpL, IN_DIM, blk * 256 + t);
  else if (blk < 48) d_split(a.W1, a.W1H, a.W1L, HID, (blk - 32) * 256 + t);
  else if (blk < 64) d_split(a.W2, a.W2H, a.W2L, HID, (blk - 48) * 256 + t);
  else d_split(a.W3, a.W3H, a.W3L, HID, (blk - 64) * 256 + t);
}

// ---------------- bucket histogram ----------------
__global__ __launch_bounds__(256) void f_bhist(Args a) {
  __shared__ int cnt[NB];
  int t = threadIdx.x;
  for (int i = t; i < NB; i += 256) cnt[i] = 0;
  __syncthreads();
  int e0 = blockIdx.x * 8192, e1 = min(e0 + 8192, N_EDGES);
  for (int e = e0 + t; e < e1; e += 256)
    atomicAdd(&cnt[a.ei[N_EDGES + e] >> 7], 1);
  __syncthreads();
  for (int i = t; i < NB; i += 256)
    if (cnt[i]) atomicAdd(&a.bsz[i], cnt[i]);
}

// ---------------- bucket exclusive scan (1 block, 256 thr x 4 slots) ----------
__global__ __launch_bounds__(256) void f_bscan(Args a) {
  __shared__ int sm[256];
  int t = threadIdx.x;
  int c[4];
  int idx0 = t * 4;
#pragma unroll
  for (int j = 0; j < 4; ++j) c[j] = (idx0 + j < NB) ? a.bsz[idx0 + j] : 0;
  int tsum = c[0] + c[1] + c[2] + c[3];
  int val = tsum;
  sm[t] = val;
  __syncthreads();
  for (int off = 1; off < 256; off <<= 1) {
    int u = (t >= off) ? sm[t - off] : 0;
    __syncthreads();
    val += u;
    sm[t] = val;
    __syncthreads();
  }
  int excl = val - tsum;
#pragma unroll
  for (int j = 0; j < 4; ++j) {
    int idx = idx0 + j;
    if (idx < NB) { a.bboff[idx] = excl; a.bcur[idx] = excl; }
    excl += c[j];
  }
  if (t == 255) a.bboff[NB] = val;  // == N_EDGES
}

// ---------------- partition edges into buckets; pack (dlocal<<17 | src) --------
__global__ __launch_bounds__(256) void f_partition(Args a) {
  __shared__ int cnt[NB];
  __shared__ int base[NB];
  int t = threadIdx.x;
  for (int i = t; i < NB; i += 256) cnt[i] = 0;
  __syncthreads();
  int e0 = blockIdx.x * 8192, e1 = min(e0 + 8192, N_EDGES);
  for (int e = e0 + t; e < e1; e += 256)
    atomicAdd(&cnt[a.ei[N_EDGES + e] >> 7], 1);
  __syncthreads();
  for (int i = t; i < NB; i += 256) {
    int c = cnt[i];
    base[i] = c ? atomicAdd(&a.bcur[i], c) : 0;
    cnt[i] = 0;
  }
  __syncthreads();
  for (int e = e0 + t; e < e1; e += 256) {
    int s = a.ei[e];
    int d = a.ei[N_EDGES + e];
    int b = d >> 7;
    int r = atomicAdd(&cnt[b], 1);
    a.pairs[base[b] + r] = ((d & 127) << 17) | s;
  }
}

// ---------------- per-bucket degrees + offs + dinv + CSR scatter ---------------
// csr now stores src << 7 (byte offset into hw16 row)
__global__ __launch_bounds__(256) void f_csrdeg(Args a) {
  __shared__ int ldeg[128];
  __shared__ int sc[128];
  __shared__ int lcur[128];
  int t = threadIdx.x;
  int b = blockIdx.x;
  int node0 = b << 7;
  int nloc = min(128, N_NODES - node0);
  int beg = a.bboff[b], end = a.bboff[b + 1];
  if (t < 128) ldeg[t] = 0;
  __syncthreads();
  for (int i = beg + t; i < end; i += 256)
    atomicAdd(&ldeg[(a.pairs[i] >> 17) & 127], 1);
  __syncthreads();
  int dv = (t < 128) ? ldeg[t] : 0;
  if (t < 128) sc[t] = dv;
  __syncthreads();
  for (int off = 1; off < 128; off <<= 1) {
    int u = (t >= off && t < 128) ? sc[t - off] : 0;
    __syncthreads();
    if (t < 128) sc[t] += u;
    __syncthreads();
  }
  if (t < nloc) {
    int o = beg + sc[t] - dv;
    a.offs[node0 + t] = o;
    lcur[t] = o;
    a.dinv[node0 + t] = rsqrtf((float)dv + 1.0f);
  }
  if (b == NB - 1 && t == 0) a.offs[N_NODES] = N_EDGES;
  __syncthreads();
  for (int i = beg + t; i < end; i += 256) {
    int p = a.pairs[i];
    int pos = atomicAdd(&lcur[(p >> 17) & 127], 1);
    a.csr[pos] = (p & 131071) << 7;
  }
}

// ---------------- per-edge meta: {src byte offset, dinv[src]} ------------------
__global__ __launch_bounds__(256) void f_wgt(Args a) {
  int e = blockIdx.x * 256 + threadIdx.x;
  if (e >= N_EDGES) return;
  int off = a.csr[e];
  float w = a.dinv[off >> 7];
  a.meta[e] = make_int2(off, __float_as_int(w));
}

// ---- pre GEMM v2: LDS-staged swizzled weights, 2 frags/wave, dbuf x prefetch ----
__global__ __launch_bounds__(256) void f_gemm_pre(Args a) {
  __shared__ _Float16 sW[2 * 64 * IN_DIM];  // hi | lo halves, XOR-swizzled (32 KB)
  int t = threadIdx.x;
  int wave = t >> 6, lane = t & 63, fi = lane & 15, quad = lane >> 4;
  int r0 = blockIdx.x * 128 + wave * 32;

  f4v xb0[8], xb1[8];
  {
    int row = r0 + fi; if (row >= N_NODES) row = N_NODES - 1;
    const float* xp = a.x + (size_t)row * IN_DIM + quad * 8;
#pragma unroll
    for (int j = 0; j < 4; ++j) {
      xb0[2 * j]     = *(const f4v*)(xp + j * 32);
      xb0[2 * j + 1] = *(const f4v*)(xp + j * 32 + 4);
    }
  }
#pragma unroll
  for (int i = 0; i < 8; ++i) {
    int c = i * 256 + t;               // 0..2047
    int h = c >> 10;                   // 0 = hi, 1 = lo
    int c2 = c & 1023;                 // chunk within half
    int n = c2 >> 4;                   // output-col row (16 chunks per row)
    const _Float16* src = (h ? a.WpL : a.WpH) + c2 * 8;
    f4v v = *(const f4v*)src;
    int off = (h << 14) | ((c2 * 16) ^ ((n & 7) << 4));
    *(f4v*)((char*)sW + off) = v;
  }
  __syncthreads();

  float bv[4];
#pragma unroll
  for (int ct = 0; ct < 4; ++ct) bv[ct] = a.bp[ct * 16 + fi];

#pragma unroll
  for (int f = 0; f < 2; ++f) {
    f4v* xcur = (f & 1) ? xb1 : xb0;
    f4v* xnxt = (f & 1) ? xb0 : xb1;
    if (f < 1) {
      int row = r0 + 16 + fi; if (row >= N_NODES) row = N_NODES - 1;
      const float* xp = a.x + (size_t)row * IN_DIM + quad * 8;
#pragma unroll
      for (int j = 0; j < 4; ++j) {
        xnxt[2 * j]     = *(const f4v*)(xp + j * 32);
        xnxt[2 * j + 1] = *(const f4v*)(xp + j * 32 + 4);
      }
    }
    f4v acc[4];
#pragma unroll
    for (int ct = 0; ct < 4; ++ct) acc[ct] = (f4v){0.f, 0.f, 0.f, 0.f};
#pragma unroll
    for (int k0i = 0; k0i < 4; ++k0i) {
      h8v ah, al;
#pragma unroll
      for (int j = 0; j < 4; ++j) {
        float v0 = xcur[2 * k0i][j], v1 = xcur[2 * k0i + 1][j];
        _Float16 h0 = (_Float16)v0, h1 = (_Float16)v1;
        ah[j] = h0;     al[j] = (_Float16)(v0 - (float)h0);
        ah[4 + j] = h1; al[4 + j] = (_Float16)(v1 - (float)h1);
      }
#pragma unroll
      for (int ct = 0; ct < 4; ++ct) {
        int n = ct * 16 + fi;
        int bo = ((n * IN_DIM + k0i * 32 + quad * 8) * 2) ^ ((n & 7) << 4);
        h8v bh = *(const h8v*)((const char*)sW + bo);
        h8v bl = *(const h8v*)((const char*)sW + 16384 + bo);
        acc[ct] = __builtin_amdgcn_mfma_f32_16x16x32_f16(ah, bh, acc[ct], 0, 0, 0);
        acc[ct] = __builtin_amdgcn_mfma_f32_16x16x32_f16(al, bh, acc[ct], 0, 0, 0);
        acc[ct] = __builtin_amdgcn_mfma_f32_16x16x32_f16(ah, bl, acc[ct], 0, 0, 0);
      }
    }
    int ro = r0 + f * 16;
#pragma unroll
    for (int ct = 0; ct < 4; ++ct) {
#pragma unroll
      for (int j = 0; j < 4; ++j) {
        int orow = ro + quad * 4 + j;
        if (orow < N_NODES)
          a.bufA16[(size_t)orow * HID + ct * 16 + fi] = (_Float16)(acc[ct][j] + bv[ct]);
      }
    }
  }
}

// ---- hidden GEMM v2: B entirely register-resident (64 VGPR), stream A dbuf ----
__global__ __launch_bounds__(256) void f_gemm64(Args a, const _Float16* __restrict__ Wh,
                                                const _Float16* __restrict__ Wl) {
  int t = threadIdx.x;
  int wave = t >> 6, lane = t & 63, fi = lane & 15, quad = lane >> 4;
  int r0 = blockIdx.x * 128 + wave * 32;

  h8v a0[2], a1[2];
  {
    int row = r0 + fi; if (row >= N_NODES) row = N_NODES - 1;
    const _Float16* xp = a.bufA16 + (size_t)row * HID + quad * 8;
    a0[0] = *(const h8v*)xp;
    a0[1] = *(const h8v*)(xp + 32);
  }
  h8v Bh[2][4], Bl[2][4];
#pragma unroll
  for (int k0i = 0; k0i < 2; ++k0i)
#pragma unroll
    for (int ct = 0; ct < 4; ++ct) {
      size_t o = (size_t)(ct * 16 + fi) * HID + k0i * 32 + quad * 8;
      Bh[k0i][ct] = *(const h8v*)(Wh + o);
      Bl[k0i][ct] = *(const h8v*)(Wl + o);
    }

#pragma unroll
  for (int f = 0; f < 2; ++f) {
    h8v* av = (f & 1) ? a1 : a0;
    h8v* nx = (f & 1) ? a0 : a1;
    if (f < 1) {
      int row = r0 + 16 + fi; if (row >= N_NODES) row = N_NODES - 1;
      const _Float16* xp = a.bufA16 + (size_t)row * HID + quad * 8;
      nx[0] = *(const h8v*)xp;
      nx[1] = *(const h8v*)(xp + 32);
    }
    f4v acc[4];
#pragma unroll
    for (int ct = 0; ct < 4; ++ct) acc[ct] = (f4v){0.f, 0.f, 0.f, 0.f};
#pragma unroll
    for (int k0i = 0; k0i < 2; ++k0i)
#pragma unroll
      for (int ct = 0; ct < 4; ++ct) {
        acc[ct] = __builtin_amdgcn_mfma_f32_16x16x32_f16(av[k0i], Bh[k0i][ct], acc[ct], 0, 0, 0);
        acc[ct] = __builtin_amdgcn_mfma_f32_16x16x32_f16(av[k0i], Bl[k0i][ct], acc[ct], 0, 0, 0);
      }
    int ro = r0 + f * 16;
#pragma unroll
    for (int ct = 0; ct < 4; ++ct)
#pragma unroll
      for (int j = 0; j < 4; ++j) {
        int orow = ro + quad * 4 + j;
        if (orow < N_NODES)
          a.hw16[(size_t)orow * HID + ct * 16 + fi] = (_Float16)acc[ct][j];
      }
  }
}

// ---- aggregation v4: lane-per-channel, SCALAR-pipe edge meta, fma_mix -----
// wave = 1 node, lane = channel. Per edge: 1 scalar-broadcast meta (s_load),
// 1 coalesced ushort gather (s-base + lane*2), 1 v_fma_mix_f32.
// out = di * (sum_e dinv[src_e]*h_src + di*h_self) + bias
template <int MODE>
__device__ __forceinline__ void d_agg(int grp, const _Float16* __restrict__ hw,
                                      const int* __restrict__ offs,
                                      const int2* __restrict__ meta,
                                      const float* __restrict__ dinv,
                                      const float* __restrict__ bias,
                                      _Float16* __restrict__ out16,
                                      float* __restrict__ out32) {
  int node = grp * 4 + (threadIdx.x >> 6);
  int lane = threadIdx.x & 63;
  int beg = __builtin_amdgcn_readfirstlane(offs[node]);
  int end = __builtin_amdgcn_readfirstlane(offs[node + 1]);
  int deg = end - beg;
  float di = dinv[node];

  float acc = 0.f;
  {  // self-loop partial: acc = h_self * di  (f16 src, f32 mul, f32 acc)
    unsigned hs = *(const unsigned short*)((const char*)hw + ((size_t)node << 7) + lane * 2);
    asm("v_fma_mix_f32 %0, %1, %2, %0 op_sel:[0,0,0] op_sel_hi:[1,0,0]"
        : "+v"(acc) : "v"(hs), "v"(di));
  }

  const int2* mp = meta + beg;
  int lb = lane * 2;
  int nfull = deg >> 4;
  for (int b = 0; b < nfull; ++b) {
    int2 mb[16];
#pragma unroll
    for (int u = 0; u < 16; ++u) mb[u] = mp[u];
    unsigned hv[16];
#pragma unroll
    for (int u = 0; u < 16; ++u)
      hv[u] = *(const unsigned short*)((const char*)hw + (unsigned)mb[u].x + lb);
#pragma unroll
    for (int u = 0; u < 16; ++u) {
      float w = __int_as_float(mb[u].y);
      asm("v_fma_mix_f32 %0, %1, %2, %0 op_sel:[0,0,0] op_sel_hi:[1,0,0]"
          : "+v"(acc) : "v"(hv[u]), "v"(w));
    }
    mp += 16;
  }
  int rem = deg & 15;
  if (rem) {
    int2 mb[16];
#pragma unroll
    for (int u = 0; u < 16; ++u) mb[u] = mp[(u < rem) ? u : 0];
    unsigned hv[16];
#pragma unroll
    for (int u = 0; u < 16; ++u)
      hv[u] = *(const unsigned short*)((const char*)hw + (unsigned)mb[u].x + lb);
#pragma unroll
    for (int u = 0; u < 16; ++u) {
      float w = (u < rem) ? __int_as_float(mb[u].y) : 0.0f;
      asm("v_fma_mix_f32 %0, %1, %2, %0 op_sel:[0,0,0] op_sel_hi:[1,0,0]"
          : "+v"(acc) : "v"(hv[u]), "v"(w));
    }
  }

  acc *= di;
  acc += bias[lane];
  if (MODE == 0) {
    out16[(size_t)node * HID + lane] = (_Float16)fmaxf(acc, 0.f);
  } else {
    float ss = acc * acc;
#pragma unroll
    for (int w = 1; w < 64; w <<= 1) ss += __shfl_xor(ss, w);
    float sc = 1.0f / fmaxf(sqrtf(ss), 1e-12f);
    out32[(size_t)node * HID + lane] = acc * sc;
  }
}

__global__ __launch_bounds__(256) void f_agg_relu(Args a, const float* bias) {
  d_agg<0>(blockIdx.x, a.hw16, a.offs, a.meta, a.dinv, bias, a.bufA16, nullptr);
}

__global__ __launch_bounds__(256) void f_agg_norm(Args a) {
  d_agg<1>(blockIdx.x, a.hw16, a.offs, a.meta, a.dinv, a.b3, nullptr, a.out);
}

extern "C" void kernel_launch(void* const* d_in, const int* in_sizes, int n_in,
                              void* d_out, int out_size, void* d_ws, size_t ws_size,
                              hipStream_t stream) {
  char* ws = (char*)d_ws;
  Args a;
  a.x  = (const float*)d_in[0];
  a.ei = (const int*)d_in[1];
  a.Wp = (const float*)d_in[2];  a.bp = (const float*)d_in[3];
  a.W1 = (const float*)d_in[4];  a.b1 = (const float*)d_in[5];
  a.W2 = (const float*)d_in[6];  a.b2 = (const float*)d_in[7];
  a.W3 = (const float*)d_in[8];  a.b3 = (const float*)d_in[9];
  a.out  = (float*)d_out;
  a.bufA16 = (_Float16*)(ws + 0);             // 12.8 MB fp16 activations
  a.hw16   = (_Float16*)(ws + 12800000);      // 12.8 MB fp16 gemm out
  a.pairs  = (int*)(ws + 25600000);           // 6.4 MB packed (dlocal<<17|src)
  a.csr    = (int*)(ws + 32000000);           // 6.4 MB (src byte offsets)
  a.offs   = (int*)(ws + 38400000);           // (N+1) ints
  a.dinv   = (float*)(ws + 38800016);         // 400 KB
  a.bsz    = (int*)(ws + 39200016);           // NB ints
  a.bboff  = (int*)(ws + 39203152);           // NB+1 ints
  a.bcur   = (int*)(ws + 39206288);           // NB ints
  a.WpH = (_Float16*)(ws + 39210000);         // 16 KB
  a.WpL = (_Float16*)(ws + 39226384);
  a.W1H = (_Float16*)(ws + 39242768);         // 8 KB each
  a.W1L = (_Float16*)(ws + 39250960);
  a.W2H = (_Float16*)(ws + 39259152);
  a.W2L = (_Float16*)(ws + 39267344);
  a.W3H = (_Float16*)(ws + 39275536);
  a.W3L = (_Float16*)(ws + 39283728);
  a.meta = (int2*)(ws + 40000000);            // 12.8 MB {off, w}

  (void)hipMemsetAsync(a.bsz, 0, NB * sizeof(int), stream);
  f_prep<<<80, 256, 0, stream>>>(a);
  f_bhist<<<196, 256, 0, stream>>>(a);
  f_bscan<<<1, 256, 0, stream>>>(a);
  f_partition<<<196, 256, 0, stream>>>(a);
  f_csrdeg<<<NB, 256, 0, stream>>>(a);
  f_wgt<<<6250, 256, 0, stream>>>(a);
  f_gemm_pre<<<NBLK_GEMM, 256, 0, stream>>>(a);
  f_gemm64<<<NBLK_GEMM, 256, 0, stream>>>(a, a.W1H, a.W1L);
  f_agg_relu<<<NGROUP, 256, 0, stream>>>(a, a.b1);
  f_gemm64<<<NBLK_GEMM, 256, 0, stream>>>(a, a.W2H, a.W2L);
  f_agg_relu<<<NGROUP, 256, 0, stream>>>(a, a.b2);
  f_gemm64<<<NBLK_GEMM, 256, 0, stream>>>(a, a.W3H, a.W3L);
  f_agg_norm<<<NGROUP, 256, 0, stream>>>(a);
}

// Round 4
// 361.294 us; speedup vs baseline: 1.2667x; 1.2667x over previous
//
#include <hip/hip_runtime.h>

#define N_NODES 100000
#define N_EDGES 1600000
#define IN_DIM 128
#define HID 64
#define NB 782               // ceil(100000 / 128) buckets of 128 nodes
#define NBLK_GEMM 782        // ceil(100000 / 128) gemm blocks (128 rows each)
#define NGROUP 25000         // N_NODES / 4 agg groups

typedef __attribute__((ext_vector_type(8))) _Float16 h8v;
typedef __attribute__((ext_vector_type(4))) float f4v;

struct Args {
  const float* x; const int* ei;
  const float* Wp; const float* bp;
  const float* W1; const float* b1;
  const float* W2; const float* b2;
  const float* W3; const float* b3;
  float* out;
  _Float16* bufA16; _Float16* hw16;
  int* pairs; int* csr; int* offs; float* dinv;
  int* bsz; int* bboff; int* bcur;
  _Float16* WpH; _Float16* WpL; _Float16* W1H; _Float16* W1L;
  _Float16* W2H; _Float16* W2L; _Float16* W3H; _Float16* W3L;
};

// f16(lo/hi half of dword) * f32 + f32 accumulate, single VALU op
__device__ __forceinline__ void fmix_lo(float& acc, unsigned hv, float w) {
  asm("v_fma_mix_f32 %0, %1, %2, %0 op_sel:[0,0,0] op_sel_hi:[1,0,0]"
      : "+v"(acc) : "v"(hv), "v"(w));
}
__device__ __forceinline__ void fmix_hi(float& acc, unsigned hv, float w) {
  asm("v_fma_mix_f32 %0, %1, %2, %0 op_sel:[1,0,0] op_sel_hi:[1,0,0]"
      : "+v"(acc) : "v"(hv), "v"(w));
}

// ---------------- weight prep: split fp32 W[K][64] -> transposed half hi/lo ----
__device__ __forceinline__ void d_split(const float* __restrict__ W,
                                        _Float16* __restrict__ hi,
                                        _Float16* __restrict__ lo, int K, int i) {
  int k = i >> 6, n = i & 63;
  float v = W[i];
  _Float16 h = (_Float16)v;
  float r = v - (float)h;
  hi[n * K + k] = h;
  lo[n * K + k] = (_Float16)r;
}

__global__ __launch_bounds__(256) void f_prep(Args a) {
  int blk = blockIdx.x, t = threadIdx.x;
  if (blk < 32) d_split(a.Wp, a.WpH, a.WpL, IN_DIM, blk * 256 + t);
  else if (blk < 48) d_split(a.W1, a.W1H, a.W1L, HID, (blk - 32) * 256 + t);
  else if (blk < 64) d_split(a.W2, a.W2H, a.W2L, HID, (blk - 48) * 256 + t);
  else d_split(a.W3, a.W3H, a.W3L, HID, (blk - 64) * 256 + t);
}

// ---------------- bucket histogram ----------------
__global__ __launch_bounds__(256) void f_bhist(Args a) {
  __shared__ int cnt[NB];
  int t = threadIdx.x;
  for (int i = t; i < NB; i += 256) cnt[i] = 0;
  __syncthreads();
  int e0 = blockIdx.x * 8192, e1 = min(e0 + 8192, N_EDGES);
  for (int e = e0 + t; e < e1; e += 256)
    atomicAdd(&cnt[a.ei[N_EDGES + e] >> 7], 1);
  __syncthreads();
  for (int i = t; i < NB; i += 256)
    if (cnt[i]) atomicAdd(&a.bsz[i], cnt[i]);
}

// ---------------- bucket exclusive scan (1 block, 256 thr x 4 slots) ----------
__global__ __launch_bounds__(256) void f_bscan(Args a) {
  __shared__ int sm[256];
  int t = threadIdx.x;
  int c[4];
  int idx0 = t * 4;
#pragma unroll
  for (int j = 0; j < 4; ++j) c[j] = (idx0 + j < NB) ? a.bsz[idx0 + j] : 0;
  int tsum = c[0] + c[1] + c[2] + c[3];
  int val = tsum;
  sm[t] = val;
  __syncthreads();
  for (int off = 1; off < 256; off <<= 1) {
    int u = (t >= off) ? sm[t - off] : 0;
    __syncthreads();
    val += u;
    sm[t] = val;
    __syncthreads();
  }
  int excl = val - tsum;
#pragma unroll
  for (int j = 0; j < 4; ++j) {
    int idx = idx0 + j;
    if (idx < NB) { a.bboff[idx] = excl; a.bcur[idx] = excl; }
    excl += c[j];
  }
  if (t == 255) a.bboff[NB] = val;  // == N_EDGES
}

// ---------------- partition edges into buckets; pack (dlocal<<17 | src) --------
__global__ __launch_bounds__(256) void f_partition(Args a) {
  __shared__ int cnt[NB];
  __shared__ int base[NB];
  int t = threadIdx.x;
  for (int i = t; i < NB; i += 256) cnt[i] = 0;
  __syncthreads();
  int e0 = blockIdx.x * 8192, e1 = min(e0 + 8192, N_EDGES);
  for (int e = e0 + t; e < e1; e += 256)
    atomicAdd(&cnt[a.ei[N_EDGES + e] >> 7], 1);
  __syncthreads();
  for (int i = t; i < NB; i += 256) {
    int c = cnt[i];
    base[i] = c ? atomicAdd(&a.bcur[i], c) : 0;
    cnt[i] = 0;
  }
  __syncthreads();
  for (int e = e0 + t; e < e1; e += 256) {
    int s = a.ei[e];
    int d = a.ei[N_EDGES + e];
    int b = d >> 7;
    int r = atomicAdd(&cnt[b], 1);
    a.pairs[base[b] + r] = ((d & 127) << 17) | s;
  }
}

// ---------------- per-bucket degrees + offs + dinv + CSR scatter ---------------
// csr stores src << 7 (byte offset of the 128B fp16 row)
__global__ __launch_bounds__(256) void f_csrdeg(Args a) {
  __shared__ int ldeg[128];
  __shared__ int sc[128];
  __shared__ int lcur[128];
  int t = threadIdx.x;
  int b = blockIdx.x;
  int node0 = b << 7;
  int nloc = min(128, N_NODES - node0);
  int beg = a.bboff[b], end = a.bboff[b + 1];
  if (t < 128) ldeg[t] = 0;
  __syncthreads();
  for (int i = beg + t; i < end; i += 256)
    atomicAdd(&ldeg[(a.pairs[i] >> 17) & 127], 1);
  __syncthreads();
  int dv = (t < 128) ? ldeg[t] : 0;
  if (t < 128) sc[t] = dv;
  __syncthreads();
  for (int off = 1; off < 128; off <<= 1) {
    int u = (t >= off && t < 128) ? sc[t - off] : 0;
    __syncthreads();
    if (t < 128) sc[t] += u;
    __syncthreads();
  }
  if (t < nloc) {
    int o = beg + sc[t] - dv;
    a.offs[node0 + t] = o;
    lcur[t] = o;
    a.dinv[node0 + t] = rsqrtf((float)dv + 1.0f);
  }
  if (b == NB - 1 && t == 0) a.offs[N_NODES] = N_EDGES;
  __syncthreads();
  for (int i = beg + t; i < end; i += 256) {
    int p = a.pairs[i];
    int pos = atomicAdd(&lcur[(p >> 17) & 127], 1);
    a.csr[pos] = (p & 131071) << 7;
  }
}

// ---- pre GEMM v2: LDS-staged swizzled weights, 2 frags/wave, dbuf x prefetch ----
__global__ __launch_bounds__(256) void f_gemm_pre(Args a) {
  __shared__ _Float16 sW[2 * 64 * IN_DIM];  // hi | lo halves, XOR-swizzled (32 KB)
  int t = threadIdx.x;
  int wave = t >> 6, lane = t & 63, fi = lane & 15, quad = lane >> 4;
  int r0 = blockIdx.x * 128 + wave * 32;

  f4v xb0[8], xb1[8];
  {
    int row = r0 + fi; if (row >= N_NODES) row = N_NODES - 1;
    const float* xp = a.x + (size_t)row * IN_DIM + quad * 8;
#pragma unroll
    for (int j = 0; j < 4; ++j) {
      xb0[2 * j]     = *(const f4v*)(xp + j * 32);
      xb0[2 * j + 1] = *(const f4v*)(xp + j * 32 + 4);
    }
  }
#pragma unroll
  for (int i = 0; i < 8; ++i) {
    int c = i * 256 + t;               // 0..2047
    int h = c >> 10;                   // 0 = hi, 1 = lo
    int c2 = c & 1023;                 // chunk within half
    int n = c2 >> 4;                   // output-col row (16 chunks per row)
    const _Float16* src = (h ? a.WpL : a.WpH) + c2 * 8;
    f4v v = *(const f4v*)src;
    int off = (h << 14) | ((c2 * 16) ^ ((n & 7) << 4));
    *(f4v*)((char*)sW + off) = v;
  }
  __syncthreads();

  float bv[4];
#pragma unroll
  for (int ct = 0; ct < 4; ++ct) bv[ct] = a.bp[ct * 16 + fi];

#pragma unroll
  for (int f = 0; f < 2; ++f) {
    f4v* xcur = (f & 1) ? xb1 : xb0;
    f4v* xnxt = (f & 1) ? xb0 : xb1;
    if (f < 1) {
      int row = r0 + 16 + fi; if (row >= N_NODES) row = N_NODES - 1;
      const float* xp = a.x + (size_t)row * IN_DIM + quad * 8;
#pragma unroll
      for (int j = 0; j < 4; ++j) {
        xnxt[2 * j]     = *(const f4v*)(xp + j * 32);
        xnxt[2 * j + 1] = *(const f4v*)(xp + j * 32 + 4);
      }
    }
    f4v acc[4];
#pragma unroll
    for (int ct = 0; ct < 4; ++ct) acc[ct] = (f4v){0.f, 0.f, 0.f, 0.f};
#pragma unroll
    for (int k0i = 0; k0i < 4; ++k0i) {
      h8v ah, al;
#pragma unroll
      for (int j = 0; j < 4; ++j) {
        float v0 = xcur[2 * k0i][j], v1 = xcur[2 * k0i + 1][j];
        _Float16 h0 = (_Float16)v0, h1 = (_Float16)v1;
        ah[j] = h0;     al[j] = (_Float16)(v0 - (float)h0);
        ah[4 + j] = h1; al[4 + j] = (_Float16)(v1 - (float)h1);
      }
#pragma unroll
      for (int ct = 0; ct < 4; ++ct) {
        int n = ct * 16 + fi;
        int bo = ((n * IN_DIM + k0i * 32 + quad * 8) * 2) ^ ((n & 7) << 4);
        h8v bh = *(const h8v*)((const char*)sW + bo);
        h8v bl = *(const h8v*)((const char*)sW + 16384 + bo);
        acc[ct] = __builtin_amdgcn_mfma_f32_16x16x32_f16(ah, bh, acc[ct], 0, 0, 0);
        acc[ct] = __builtin_amdgcn_mfma_f32_16x16x32_f16(al, bh, acc[ct], 0, 0, 0);
        acc[ct] = __builtin_amdgcn_mfma_f32_16x16x32_f16(ah, bl, acc[ct], 0, 0, 0);
      }
    }
    int ro = r0 + f * 16;
#pragma unroll
    for (int ct = 0; ct < 4; ++ct) {
#pragma unroll
      for (int j = 0; j < 4; ++j) {
        int orow = ro + quad * 4 + j;
        if (orow < N_NODES)
          a.bufA16[(size_t)orow * HID + ct * 16 + fi] = (_Float16)(acc[ct][j] + bv[ct]);
      }
    }
  }
}

// ---- hidden GEMM v2: B entirely register-resident (64 VGPR), stream A dbuf ----
__global__ __launch_bounds__(256) void f_gemm64(Args a, const _Float16* __restrict__ Wh,
                                                const _Float16* __restrict__ Wl) {
  int t = threadIdx.x;
  int wave = t >> 6, lane = t & 63, fi = lane & 15, quad = lane >> 4;
  int r0 = blockIdx.x * 128 + wave * 32;

  h8v a0[2], a1[2];
  {
    int row = r0 + fi; if (row >= N_NODES) row = N_NODES - 1;
    const _Float16* xp = a.bufA16 + (size_t)row * HID + quad * 8;
    a0[0] = *(const h8v*)xp;
    a0[1] = *(const h8v*)(xp + 32);
  }
  h8v Bh[2][4], Bl[2][4];
#pragma unroll
  for (int k0i = 0; k0i < 2; ++k0i)
#pragma unroll
    for (int ct = 0; ct < 4; ++ct) {
      size_t o = (size_t)(ct * 16 + fi) * HID + k0i * 32 + quad * 8;
      Bh[k0i][ct] = *(const h8v*)(Wh + o);
      Bl[k0i][ct] = *(const h8v*)(Wl + o);
    }

#pragma unroll
  for (int f = 0; f < 2; ++f) {
    h8v* av = (f & 1) ? a1 : a0;
    h8v* nx = (f & 1) ? a0 : a1;
    if (f < 1) {
      int row = r0 + 16 + fi; if (row >= N_NODES) row = N_NODES - 1;
      const _Float16* xp = a.bufA16 + (size_t)row * HID + quad * 8;
      nx[0] = *(const h8v*)xp;
      nx[1] = *(const h8v*)(xp + 32);
    }
    f4v acc[4];
#pragma unroll
    for (int ct = 0; ct < 4; ++ct) acc[ct] = (f4v){0.f, 0.f, 0.f, 0.f};
#pragma unroll
    for (int k0i = 0; k0i < 2; ++k0i)
#pragma unroll
      for (int ct = 0; ct < 4; ++ct) {
        acc[ct] = __builtin_amdgcn_mfma_f32_16x16x32_f16(av[k0i], Bh[k0i][ct], acc[ct], 0, 0, 0);
        acc[ct] = __builtin_amdgcn_mfma_f32_16x16x32_f16(av[k0i], Bl[k0i][ct], acc[ct], 0, 0, 0);
      }
    int ro = r0 + f * 16;
#pragma unroll
    for (int ct = 0; ct < 4; ++ct)
#pragma unroll
      for (int j = 0; j < 4; ++j) {
        int orow = ro + quad * 4 + j;
        if (orow < N_NODES)
          a.hw16[(size_t)orow * HID + ct * 16 + fi] = (_Float16)acc[ct][j];
      }
  }
}

// ---- aggregation v5: round-1 oct-parallel structure + fma_mix + stride-16 ----
// wave = 1 node; oct j handles edges (pos-beg) % 8 == j, 2-deep per pass.
// Per edge: 1 coalesced 16B/lane row gather (8 lanes cover the 128B row),
// weight = dinv[src] (di factored out, applied once post-reduce).
// MODE 0: bias+relu -> fp16 bufA16    MODE 1: bias + L2 normalize -> fp32 out
template <int MODE>
__device__ __forceinline__ void d_agg(int grp, const _Float16* __restrict__ hw,
                                      const int* __restrict__ offs,
                                      const int* __restrict__ csr,
                                      const float* __restrict__ dinv,
                                      const float* __restrict__ bias,
                                      _Float16* __restrict__ out16,
                                      float* __restrict__ out32) {
  int node = grp * 4 + (threadIdx.x >> 6);
  int lane = threadIdx.x & 63;
  int oct = lane >> 3;
  int fi = lane & 7;
  float di = dinv[node];
  int beg = offs[node];
  int end = offs[node + 1];
  int lb = fi * 16;  // byte offset within 128B row
  const char* hwb = (const char*)hw;

  float acc[8];
#pragma unroll
  for (int c = 0; c < 8; ++c) acc[c] = 0.f;

  if (oct == 0) {  // self-loop: h_self * di  (post-reduce *di -> di^2)
    uint4 hv = *(const uint4*)(hwb + ((size_t)node << 7) + lb);
    fmix_lo(acc[0], hv.x, di); fmix_hi(acc[1], hv.x, di);
    fmix_lo(acc[2], hv.y, di); fmix_hi(acc[3], hv.y, di);
    fmix_lo(acc[4], hv.z, di); fmix_hi(acc[5], hv.z, di);
    fmix_lo(acc[6], hv.w, di); fmix_hi(acc[7], hv.w, di);
  }
  for (int e0 = beg + oct; e0 < end; e0 += 16) {
    int off0 = csr[e0];                 // always valid (loop cond)
    int e1 = e0 + 8;
    bool v1 = e1 < end;
    int off1 = csr[v1 ? e1 : beg];
    float w0 = dinv[(unsigned)off0 >> 7];
    float w1 = v1 ? dinv[(unsigned)off1 >> 7] : 0.0f;
    uint4 h0 = *(const uint4*)(hwb + (unsigned)off0 + lb);
    uint4 h1 = *(const uint4*)(hwb + (unsigned)off1 + lb);
    fmix_lo(acc[0], h0.x, w0); fmix_hi(acc[1], h0.x, w0);
    fmix_lo(acc[2], h0.y, w0); fmix_hi(acc[3], h0.y, w0);
    fmix_lo(acc[4], h0.z, w0); fmix_hi(acc[5], h0.z, w0);
    fmix_lo(acc[6], h0.w, w0); fmix_hi(acc[7], h0.w, w0);
    fmix_lo(acc[0], h1.x, w1); fmix_hi(acc[1], h1.x, w1);
    fmix_lo(acc[2], h1.y, w1); fmix_hi(acc[3], h1.y, w1);
    fmix_lo(acc[4], h1.z, w1); fmix_hi(acc[5], h1.z, w1);
    fmix_lo(acc[6], h1.w, w1); fmix_hi(acc[7], h1.w, w1);
  }
#pragma unroll
  for (int c = 0; c < 8; ++c) {
    float v = acc[c];
    v += __shfl_xor(v, 8);
    v += __shfl_xor(v, 16);
    v += __shfl_xor(v, 32);
    acc[c] = v;
  }
  if (oct == 0) {
#pragma unroll
    for (int c = 0; c < 8; ++c) acc[c] = acc[c] * di + bias[fi * 8 + c];
    if (MODE == 0) {
      h8v o;
#pragma unroll
      for (int c = 0; c < 8; ++c) o[c] = (_Float16)fmaxf(acc[c], 0.f);
      *(h8v*)(out16 + (size_t)node * HID + fi * 8) = o;
    } else {
      float ss = 0.f;
#pragma unroll
      for (int c = 0; c < 8; ++c) ss += acc[c] * acc[c];
      ss += __shfl_xor(ss, 1);
      ss += __shfl_xor(ss, 2);
      ss += __shfl_xor(ss, 4);
      float sc = 1.0f / fmaxf(sqrtf(ss), 1e-12f);
      f4v o0 = {acc[0] * sc, acc[1] * sc, acc[2] * sc, acc[3] * sc};
      f4v o1 = {acc[4] * sc, acc[5] * sc, acc[6] * sc, acc[7] * sc};
      *(f4v*)(out32 + (size_t)node * HID + fi * 8) = o0;
      *(f4v*)(out32 + (size_t)node * HID + fi * 8 + 4) = o1;
    }
  }
}

__global__ __launch_bounds__(256) void f_agg_relu(Args a, const float* bias) {
  d_agg<0>(blockIdx.x, a.hw16, a.offs, a.csr, a.dinv, bias, a.bufA16, nullptr);
}

__global__ __launch_bounds__(256) void f_agg_norm(Args a) {
  d_agg<1>(blockIdx.x, a.hw16, a.offs, a.csr, a.dinv, a.b3, nullptr, a.out);
}

extern "C" void kernel_launch(void* const* d_in, const int* in_sizes, int n_in,
                              void* d_out, int out_size, void* d_ws, size_t ws_size,
                              hipStream_t stream) {
  char* ws = (char*)d_ws;
  Args a;
  a.x  = (const float*)d_in[0];
  a.ei = (const int*)d_in[1];
  a.Wp = (const float*)d_in[2];  a.bp = (const float*)d_in[3];
  a.W1 = (const float*)d_in[4];  a.b1 = (const float*)d_in[5];
  a.W2 = (const float*)d_in[6];  a.b2 = (const float*)d_in[7];
  a.W3 = (const float*)d_in[8];  a.b3 = (const float*)d_in[9];
  a.out  = (float*)d_out;
  a.bufA16 = (_Float16*)(ws + 0);             // 12.8 MB fp16 activations
  a.hw16   = (_Float16*)(ws + 12800000);      // 12.8 MB fp16 gemm out
  a.pairs  = (int*)(ws + 25600000);           // 6.4 MB packed (dlocal<<17|src)
  a.csr    = (int*)(ws + 32000000);           // 6.4 MB (src byte offsets)
  a.offs   = (int*)(ws + 38400000);           // (N+1) ints
  a.dinv   = (float*)(ws + 38800016);         // 400 KB
  a.bsz    = (int*)(ws + 39200016);           // NB ints
  a.bboff  = (int*)(ws + 39203152);           // NB+1 ints
  a.bcur   = (int*)(ws + 39206288);           // NB ints
  a.WpH = (_Float16*)(ws + 39210000);         // 16 KB
  a.WpL = (_Float16*)(ws + 39226384);
  a.W1H = (_Float16*)(ws + 39242768);         // 8 KB each
  a.W1L = (_Float16*)(ws + 39250960);
  a.W2H = (_Float16*)(ws + 39259152);
  a.W2L = (_Float16*)(ws + 39267344);
  a.W3H = (_Float16*)(ws + 39275536);
  a.W3L = (_Float16*)(ws + 39283728);

  (void)hipMemsetAsync(a.bsz, 0, NB * sizeof(int), stream);
  f_prep<<<80, 256, 0, stream>>>(a);
  f_bhist<<<196, 256, 0, stream>>>(a);
  f_bscan<<<1, 256, 0, stream>>>(a);
  f_partition<<<196, 256, 0, stream>>>(a);
  f_csrdeg<<<NB, 256, 0, stream>>>(a);
  f_gemm_pre<<<NBLK_GEMM, 256, 0, stream>>>(a);
  f_gemm64<<<NBLK_GEMM, 256, 0, stream>>>(a, a.W1H, a.W1L);
  f_agg_relu<<<NGROUP, 256, 0, stream>>>(a, a.b1);
  f_gemm64<<<NBLK_GEMM, 256, 0, stream>>>(a, a.W2H, a.W2L);
  f_agg_relu<<<NGROUP, 256, 0, stream>>>(a, a.b2);
  f_gemm64<<<NBLK_GEMM, 256, 0, stream>>>(a, a.W3H, a.W3L);
  f_agg_norm<<<NGROUP, 256, 0, stream>>>(a);
}

// Round 5
// 333.081 us; speedup vs baseline: 1.3740x; 1.0847x over previous
//
#include <hip/hip_runtime.h>

#define N_NODES 100000
#define N_EDGES 1600000
#define IN_DIM 128
#define HID 64
#define NB 782               // ceil(100000 / 128) buckets of 128 nodes
#define NBLK_GEMM 782        // ceil(100000 / 128) gemm blocks (128 rows each)
#define NGROUP16 6250        // N_NODES / 16 fused-agg blocks

typedef __attribute__((ext_vector_type(8))) _Float16 h8v;
typedef __attribute__((ext_vector_type(4))) float f4v;

struct Args {
  const float* x; const int* ei;
  const float* Wp; const float* bp;
  const float* W1; const float* b1;
  const float* W2; const float* b2;
  const float* W3; const float* b3;
  float* out;
  _Float16* bufA16; _Float16* hw16;
  int* pairs; int* csr; int* offs; float* dinv;
  int* bsz; int* bboff; int* bcur;
  _Float16* WpH; _Float16* WpL; _Float16* W1H; _Float16* W1L;
  _Float16* W2H; _Float16* W2L; _Float16* W3H; _Float16* W3L;
};

// f16(lo/hi half of dword) * f32 + f32 accumulate, single VALU op
__device__ __forceinline__ void fmix_lo(float& acc, unsigned hv, float w) {
  asm("v_fma_mix_f32 %0, %1, %2, %0 op_sel:[0,0,0] op_sel_hi:[1,0,0]"
      : "+v"(acc) : "v"(hv), "v"(w));
}
__device__ __forceinline__ void fmix_hi(float& acc, unsigned hv, float w) {
  asm("v_fma_mix_f32 %0, %1, %2, %0 op_sel:[1,0,0] op_sel_hi:[1,0,0]"
      : "+v"(acc) : "v"(hv), "v"(w));
}

// ---------------- weight prep: split fp32 W[K][64] -> transposed half hi/lo ----
__device__ __forceinline__ void d_split(const float* __restrict__ W,
                                        _Float16* __restrict__ hi,
                                        _Float16* __restrict__ lo, int K, int i) {
  int k = i >> 6, n = i & 63;
  float v = W[i];
  _Float16 h = (_Float16)v;
  float r = v - (float)h;
  hi[n * K + k] = h;
  lo[n * K + k] = (_Float16)r;
}

__global__ __launch_bounds__(256) void f_prep(Args a) {
  int blk = blockIdx.x, t = threadIdx.x;
  if (blk < 32) d_split(a.Wp, a.WpH, a.WpL, IN_DIM, blk * 256 + t);
  else if (blk < 48) d_split(a.W1, a.W1H, a.W1L, HID, (blk - 32) * 256 + t);
  else if (blk < 64) d_split(a.W2, a.W2H, a.W2L, HID, (blk - 48) * 256 + t);
  else d_split(a.W3, a.W3H, a.W3L, HID, (blk - 64) * 256 + t);
}

// ---------------- bucket histogram ----------------
__global__ __launch_bounds__(256) void f_bhist(Args a) {
  __shared__ int cnt[NB];
  int t = threadIdx.x;
  for (int i = t; i < NB; i += 256) cnt[i] = 0;
  __syncthreads();
  int e0 = blockIdx.x * 8192, e1 = min(e0 + 8192, N_EDGES);
  for (int e = e0 + t; e < e1; e += 256)
    atomicAdd(&cnt[a.ei[N_EDGES + e] >> 7], 1);
  __syncthreads();
  for (int i = t; i < NB; i += 256)
    if (cnt[i]) atomicAdd(&a.bsz[i], cnt[i]);
}

// ---------------- bucket exclusive scan (1 block, 256 thr x 4 slots) ----------
__global__ __launch_bounds__(256) void f_bscan(Args a) {
  __shared__ int sm[256];
  int t = threadIdx.x;
  int c[4];
  int idx0 = t * 4;
#pragma unroll
  for (int j = 0; j < 4; ++j) c[j] = (idx0 + j < NB) ? a.bsz[idx0 + j] : 0;
  int tsum = c[0] + c[1] + c[2] + c[3];
  int val = tsum;
  sm[t] = val;
  __syncthreads();
  for (int off = 1; off < 256; off <<= 1) {
    int u = (t >= off) ? sm[t - off] : 0;
    __syncthreads();
    val += u;
    sm[t] = val;
    __syncthreads();
  }
  int excl = val - tsum;
#pragma unroll
  for (int j = 0; j < 4; ++j) {
    int idx = idx0 + j;
    if (idx < NB) { a.bboff[idx] = excl; a.bcur[idx] = excl; }
    excl += c[j];
  }
  if (t == 255) a.bboff[NB] = val;  // == N_EDGES
}

// ---------------- partition edges into buckets; pack (dlocal<<17 | src) --------
__global__ __launch_bounds__(256) void f_partition(Args a) {
  __shared__ int cnt[NB];
  __shared__ int base[NB];
  int t = threadIdx.x;
  for (int i = t; i < NB; i += 256) cnt[i] = 0;
  __syncthreads();
  int e0 = blockIdx.x * 8192, e1 = min(e0 + 8192, N_EDGES);
  for (int e = e0 + t; e < e1; e += 256)
    atomicAdd(&cnt[a.ei[N_EDGES + e] >> 7], 1);
  __syncthreads();
  for (int i = t; i < NB; i += 256) {
    int c = cnt[i];
    base[i] = c ? atomicAdd(&a.bcur[i], c) : 0;
    cnt[i] = 0;
  }
  __syncthreads();
  for (int e = e0 + t; e < e1; e += 256) {
    int s = a.ei[e];
    int d = a.ei[N_EDGES + e];
    int b = d >> 7;
    int r = atomicAdd(&cnt[b], 1);
    a.pairs[base[b] + r] = ((d & 127) << 17) | s;
  }
}

// ---------------- per-bucket degrees + offs + dinv + CSR scatter ---------------
// csr stores src << 7 (byte offset of the 128B fp16 row)
__global__ __launch_bounds__(256) void f_csrdeg(Args a) {
  __shared__ int ldeg[128];
  __shared__ int sc[128];
  __shared__ int lcur[128];
  int t = threadIdx.x;
  int b = blockIdx.x;
  int node0 = b << 7;
  int nloc = min(128, N_NODES - node0);
  int beg = a.bboff[b], end = a.bboff[b + 1];
  if (t < 128) ldeg[t] = 0;
  __syncthreads();
  for (int i = beg + t; i < end; i += 256)
    atomicAdd(&ldeg[(a.pairs[i] >> 17) & 127], 1);
  __syncthreads();
  int dv = (t < 128) ? ldeg[t] : 0;
  if (t < 128) sc[t] = dv;
  __syncthreads();
  for (int off = 1; off < 128; off <<= 1) {
    int u = (t >= off && t < 128) ? sc[t - off] : 0;
    __syncthreads();
    if (t < 128) sc[t] += u;
    __syncthreads();
  }
  if (t < nloc) {
    int o = beg + sc[t] - dv;
    a.offs[node0 + t] = o;
    lcur[t] = o;
    a.dinv[node0 + t] = rsqrtf((float)dv + 1.0f);
  }
  if (b == NB - 1 && t == 0) a.offs[N_NODES] = N_EDGES;
  __syncthreads();
  for (int i = beg + t; i < end; i += 256) {
    int p = a.pairs[i];
    int pos = atomicAdd(&lcur[(p >> 17) & 127], 1);
    a.csr[pos] = (p & 131071) << 7;
  }
}

// ---- pre GEMM v2: LDS-staged swizzled weights, 2 frags/wave, dbuf x prefetch ----
__global__ __launch_bounds__(256) void f_gemm_pre(Args a) {
  __shared__ _Float16 sW[2 * 64 * IN_DIM];  // hi | lo halves, XOR-swizzled (32 KB)
  int t = threadIdx.x;
  int wave = t >> 6, lane = t & 63, fi = lane & 15, quad = lane >> 4;
  int r0 = blockIdx.x * 128 + wave * 32;

  f4v xb0[8], xb1[8];
  {
    int row = r0 + fi; if (row >= N_NODES) row = N_NODES - 1;
    const float* xp = a.x + (size_t)row * IN_DIM + quad * 8;
#pragma unroll
    for (int j = 0; j < 4; ++j) {
      xb0[2 * j]     = *(const f4v*)(xp + j * 32);
      xb0[2 * j + 1] = *(const f4v*)(xp + j * 32 + 4);
    }
  }
#pragma unroll
  for (int i = 0; i < 8; ++i) {
    int c = i * 256 + t;               // 0..2047
    int h = c >> 10;                   // 0 = hi, 1 = lo
    int c2 = c & 1023;                 // chunk within half
    int n = c2 >> 4;                   // output-col row (16 chunks per row)
    const _Float16* src = (h ? a.WpL : a.WpH) + c2 * 8;
    f4v v = *(const f4v*)src;
    int off = (h << 14) | ((c2 * 16) ^ ((n & 7) << 4));
    *(f4v*)((char*)sW + off) = v;
  }
  __syncthreads();

  float bv[4];
#pragma unroll
  for (int ct = 0; ct < 4; ++ct) bv[ct] = a.bp[ct * 16 + fi];

#pragma unroll
  for (int f = 0; f < 2; ++f) {
    f4v* xcur = (f & 1) ? xb1 : xb0;
    f4v* xnxt = (f & 1) ? xb0 : xb1;
    if (f < 1) {
      int row = r0 + 16 + fi; if (row >= N_NODES) row = N_NODES - 1;
      const float* xp = a.x + (size_t)row * IN_DIM + quad * 8;
#pragma unroll
      for (int j = 0; j < 4; ++j) {
        xnxt[2 * j]     = *(const f4v*)(xp + j * 32);
        xnxt[2 * j + 1] = *(const f4v*)(xp + j * 32 + 4);
      }
    }
    f4v acc[4];
#pragma unroll
    for (int ct = 0; ct < 4; ++ct) acc[ct] = (f4v){0.f, 0.f, 0.f, 0.f};
#pragma unroll
    for (int k0i = 0; k0i < 4; ++k0i) {
      h8v ah, al;
#pragma unroll
      for (int j = 0; j < 4; ++j) {
        float v0 = xcur[2 * k0i][j], v1 = xcur[2 * k0i + 1][j];
        _Float16 h0 = (_Float16)v0, h1 = (_Float16)v1;
        ah[j] = h0;     al[j] = (_Float16)(v0 - (float)h0);
        ah[4 + j] = h1; al[4 + j] = (_Float16)(v1 - (float)h1);
      }
#pragma unroll
      for (int ct = 0; ct < 4; ++ct) {
        int n = ct * 16 + fi;
        int bo = ((n * IN_DIM + k0i * 32 + quad * 8) * 2) ^ ((n & 7) << 4);
        h8v bh = *(const h8v*)((const char*)sW + bo);
        h8v bl = *(const h8v*)((const char*)sW + 16384 + bo);
        acc[ct] = __builtin_amdgcn_mfma_f32_16x16x32_f16(ah, bh, acc[ct], 0, 0, 0);
        acc[ct] = __builtin_amdgcn_mfma_f32_16x16x32_f16(al, bh, acc[ct], 0, 0, 0);
        acc[ct] = __builtin_amdgcn_mfma_f32_16x16x32_f16(ah, bl, acc[ct], 0, 0, 0);
      }
    }
    int ro = r0 + f * 16;
#pragma unroll
    for (int ct = 0; ct < 4; ++ct) {
#pragma unroll
      for (int j = 0; j < 4; ++j) {
        int orow = ro + quad * 4 + j;
        if (orow < N_NODES)
          a.bufA16[(size_t)orow * HID + ct * 16 + fi] = (_Float16)(acc[ct][j] + bv[ct]);
      }
    }
  }
}

// ---- fused aggregate + GEMM (v6) -------------------------------------------
// agg(h W) == (agg h) W. Block = 16 nodes (4 waves x 4 nodes sequential).
// Phase 1: round-4 gather loop (byte-identical memory shape) accumulates
//   g = di*(sum_s dinv_s h_s + di*h_self) in fp32; hi/lo fp16 into swizzled LDS.
// Phase 2: each wave computes one 16-out-ch tile for all 16 nodes via 6 MFMAs
//   (gemm64's exact fragment pattern), then bias+relu (MODE 0) or bias+L2
//   normalize via cross-wave LDS reduce (MODE 1).
template <int MODE>
__global__ __launch_bounds__(256) void f_aggw(Args a, const _Float16* __restrict__ hsrc,
                                              const _Float16* __restrict__ Wh,
                                              const _Float16* __restrict__ Wl,
                                              const float* __restrict__ bias,
                                              _Float16* __restrict__ out16,
                                              float* __restrict__ out32) {
  __shared__ char sG[2][2048];     // [hi|lo][16 rows x 128B], byte ^= (row&7)<<4
  __shared__ float sSS[4][16];     // per-wave partial sum-of-squares (MODE 1)
  int t = threadIdx.x;
  int wave = t >> 6, lane = t & 63, oct = lane >> 3, fi = lane & 7;
  int node0 = blockIdx.x * 16;     // N_NODES == 6250*16, no bounds checks
  const char* hwb = (const char*)hsrc;
  int lb = fi * 16;

  for (int n = 0; n < 4; ++n) {
    int node = node0 + wave * 4 + n;
    float di = a.dinv[node];
    int beg = a.offs[node];
    int end = a.offs[node + 1];
    float acc[8];
#pragma unroll
    for (int c = 0; c < 8; ++c) acc[c] = 0.f;

    if (oct == 0) {  // self-loop: h_self * di (post-scale by di -> di^2)
      uint4 hv = *(const uint4*)(hwb + ((size_t)node << 7) + lb);
      fmix_lo(acc[0], hv.x, di); fmix_hi(acc[1], hv.x, di);
      fmix_lo(acc[2], hv.y, di); fmix_hi(acc[3], hv.y, di);
      fmix_lo(acc[4], hv.z, di); fmix_hi(acc[5], hv.z, di);
      fmix_lo(acc[6], hv.w, di); fmix_hi(acc[7], hv.w, di);
    }
    for (int e0 = beg + oct; e0 < end; e0 += 16) {
      int off0 = a.csr[e0];
      int e1 = e0 + 8;
      bool v1 = e1 < end;
      int off1 = a.csr[v1 ? e1 : beg];
      float w0 = a.dinv[(unsigned)off0 >> 7];
      float w1 = v1 ? a.dinv[(unsigned)off1 >> 7] : 0.0f;
      uint4 h0 = *(const uint4*)(hwb + (unsigned)off0 + lb);
      uint4 h1 = *(const uint4*)(hwb + (unsigned)off1 + lb);
      fmix_lo(acc[0], h0.x, w0); fmix_hi(acc[1], h0.x, w0);
      fmix_lo(acc[2], h0.y, w0); fmix_hi(acc[3], h0.y, w0);
      fmix_lo(acc[4], h0.z, w0); fmix_hi(acc[5], h0.z, w0);
      fmix_lo(acc[6], h0.w, w0); fmix_hi(acc[7], h0.w, w0);
      fmix_lo(acc[0], h1.x, w1); fmix_hi(acc[1], h1.x, w1);
      fmix_lo(acc[2], h1.y, w1); fmix_hi(acc[3], h1.y, w1);
      fmix_lo(acc[4], h1.z, w1); fmix_hi(acc[5], h1.z, w1);
      fmix_lo(acc[6], h1.w, w1); fmix_hi(acc[7], h1.w, w1);
    }
#pragma unroll
    for (int c = 0; c < 8; ++c) {
      float v = acc[c];
      v += __shfl_xor(v, 8);
      v += __shfl_xor(v, 16);
      v += __shfl_xor(v, 32);
      acc[c] = v;
    }
    if (oct == 0) {  // g = acc * di, split hi/lo, stage to LDS
      int row = wave * 4 + n;
      h8v gh, gl;
#pragma unroll
      for (int c = 0; c < 8; ++c) {
        float g = acc[c] * di;
        _Float16 h = (_Float16)g;
        gh[c] = h;
        gl[c] = (_Float16)(g - (float)h);
      }
      int off = (row * 128 + fi * 16) ^ ((row & 7) << 4);
      *(h8v*)(&sG[0][0] + off) = gh;
      *(h8v*)(&sG[1][0] + off) = gl;
    }
  }
  __syncthreads();

  // MFMA phase: wave w -> out-ch tile [w*16, w*16+16) for all 16 nodes
  int r15 = lane & 15, quad = lane >> 4;
  f4v acc4 = {0.f, 0.f, 0.f, 0.f};
#pragma unroll
  for (int k0i = 0; k0i < 2; ++k0i) {
    int ao = (r15 * 128 + k0i * 64 + quad * 16) ^ ((r15 & 7) << 4);
    h8v ah = *(const h8v*)(&sG[0][0] + ao);
    h8v al = *(const h8v*)(&sG[1][0] + ao);
    size_t bo = (size_t)(wave * 16 + r15) * HID + k0i * 32 + quad * 8;
    h8v bh = *(const h8v*)(Wh + bo);
    h8v bl = *(const h8v*)(Wl + bo);
    acc4 = __builtin_amdgcn_mfma_f32_16x16x32_f16(ah, bh, acc4, 0, 0, 0);
    acc4 = __builtin_amdgcn_mfma_f32_16x16x32_f16(al, bh, acc4, 0, 0, 0);
    acc4 = __builtin_amdgcn_mfma_f32_16x16x32_f16(ah, bl, acc4, 0, 0, 0);
  }
  // C layout: node = quad*4 + j (block-local), out-ch = wave*16 + r15
  float bv = bias[wave * 16 + r15];
  if (MODE == 0) {
#pragma unroll
    for (int j = 0; j < 4; ++j) {
      int nl = quad * 4 + j;
      out16[(size_t)(node0 + nl) * HID + wave * 16 + r15] =
          (_Float16)fmaxf(acc4[j] + bv, 0.f);
    }
  } else {
    float val[4], ssj[4];
#pragma unroll
    for (int j = 0; j < 4; ++j) { val[j] = acc4[j] + bv; ssj[j] = val[j] * val[j]; }
#pragma unroll
    for (int m = 1; m < 16; m <<= 1) {
#pragma unroll
      for (int j = 0; j < 4; ++j) ssj[j] += __shfl_xor(ssj[j], m);
    }
    if (r15 == 0) {
#pragma unroll
      for (int j = 0; j < 4; ++j) sSS[wave][quad * 4 + j] = ssj[j];
    }
    __syncthreads();
#pragma unroll
    for (int j = 0; j < 4; ++j) {
      int nl = quad * 4 + j;
      float tot = sSS[0][nl] + sSS[1][nl] + sSS[2][nl] + sSS[3][nl];
      float sc = 1.0f / fmaxf(sqrtf(tot), 1e-12f);
      out32[(size_t)(node0 + nl) * HID + wave * 16 + r15] = val[j] * sc;
    }
  }
}

extern "C" void kernel_launch(void* const* d_in, const int* in_sizes, int n_in,
                              void* d_out, int out_size, void* d_ws, size_t ws_size,
                              hipStream_t stream) {
  char* ws = (char*)d_ws;
  Args a;
  a.x  = (const float*)d_in[0];
  a.ei = (const int*)d_in[1];
  a.Wp = (const float*)d_in[2];  a.bp = (const float*)d_in[3];
  a.W1 = (const float*)d_in[4];  a.b1 = (const float*)d_in[5];
  a.W2 = (const float*)d_in[6];  a.b2 = (const float*)d_in[7];
  a.W3 = (const float*)d_in[8];  a.b3 = (const float*)d_in[9];
  a.out  = (float*)d_out;
  a.bufA16 = (_Float16*)(ws + 0);             // 12.8 MB fp16 activations A0
  a.hw16   = (_Float16*)(ws + 12800000);      // 12.8 MB fp16 activations A1
  a.pairs  = (int*)(ws + 25600000);           // 6.4 MB packed (dlocal<<17|src)
  a.csr    = (int*)(ws + 32000000);           // 6.4 MB (src byte offsets)
  a.offs   = (int*)(ws + 38400000);           // (N+1) ints
  a.dinv   = (float*)(ws + 38800016);         // 400 KB
  a.bsz    = (int*)(ws + 39200016);           // NB ints
  a.bboff  = (int*)(ws + 39203152);           // NB+1 ints
  a.bcur   = (int*)(ws + 39206288);           // NB ints
  a.WpH = (_Float16*)(ws + 39210000);         // 16 KB
  a.WpL = (_Float16*)(ws + 39226384);
  a.W1H = (_Float16*)(ws + 39242768);         // 8 KB each
  a.W1L = (_Float16*)(ws + 39250960);
  a.W2H = (_Float16*)(ws + 39259152);
  a.W2L = (_Float16*)(ws + 39267344);
  a.W3H = (_Float16*)(ws + 39275536);
  a.W3L = (_Float16*)(ws + 39283728);

  (void)hipMemsetAsync(a.bsz, 0, NB * sizeof(int), stream);
  f_prep<<<80, 256, 0, stream>>>(a);
  f_bhist<<<196, 256, 0, stream>>>(a);
  f_bscan<<<1, 256, 0, stream>>>(a);
  f_partition<<<196, 256, 0, stream>>>(a);
  f_csrdeg<<<NB, 256, 0, stream>>>(a);
  f_gemm_pre<<<NBLK_GEMM, 256, 0, stream>>>(a);
  f_aggw<0><<<NGROUP16, 256, 0, stream>>>(a, a.bufA16, a.W1H, a.W1L, a.b1, a.hw16, nullptr);
  f_aggw<0><<<NGROUP16, 256, 0, stream>>>(a, a.hw16, a.W2H, a.W2L, a.b2, a.bufA16, nullptr);
  f_aggw<1><<<NGROUP16, 256, 0, stream>>>(a, a.bufA16, a.W3H, a.W3L, a.b3, nullptr, a.out);
}